// Round 8
// baseline (427.727 us; speedup 1.0000x reference)
//
#include <hip/hip_runtime.h>
#include <math.h>

#define BB 2048
#define SS 96
#define DD 7
#define HH 64
#define H2 16
#define FASTR 776  // fa16 / faS row stride (f16): 97*16B
#define HST2 72    // k_bilstm h dbuf row stride (f16)
#define LO_ST 72   // k_attn loB stride (f16)
#define QK_ST 68   // k_attn q/tk stride (f16), b64-aligned
#define TV_ST 104  // k_attn tvT stride (f16)
#define P_ST 104   // k_attn p stride (f16), overlays q+tk region

typedef _Float16 f16x8 __attribute__((ext_vector_type(8)));
typedef _Float16 f16x4 __attribute__((ext_vector_type(4)));
typedef float f32x4 __attribute__((ext_vector_type(4)));

// Fast rcp-based nonlinearities (no -ffast-math: IEEE div = ~11 instrs).
__device__ __forceinline__ float frcp(float x) { return __builtin_amdgcn_rcpf(x); }
__device__ __forceinline__ float sigm(float x) { return frcp(1.0f + __expf(-x)); }
__device__ __forceinline__ float tanh_f(float x) { return 1.0f - 2.0f * frcp(__expf(2.0f * x) + 1.0f); }
__device__ __forceinline__ float rl(float v, int l) {
    return __int_as_float(__builtin_amdgcn_readlane(__float_as_int(v), l));
}
// load 8 consecutive fp32 (16B-aligned) -> f16x8 fragment
__device__ __forceinline__ f16x8 frag_from_f32(const float* base) {
    const float4* p = (const float4*)base;
    float4 a = p[0], b = p[1];
    f16x8 r;
    r[0] = (_Float16)a.x; r[1] = (_Float16)a.y; r[2] = (_Float16)a.z; r[3] = (_Float16)a.w;
    r[4] = (_Float16)b.x; r[5] = (_Float16)b.y; r[6] = (_Float16)b.z; r[7] = (_Float16)b.w;
    return r;
}
// two ds_read_b64 -> f16x8 (for 8B-aligned strides)
__device__ __forceinline__ f16x8 ld2x4(const _Float16* p) {
    f16x4 a = *(const f16x4*)p;
    f16x4 b = *(const f16x4*)(p + 4);
    f16x8 r;
    r[0]=a[0]; r[1]=a[1]; r[2]=a[2]; r[3]=a[3];
    r[4]=b[0]; r[5]=b[1]; r[6]=b[2]; r[7]=b[3];
    return r;
}

// ---------------- Kernel 0: weight prep (f16 conversion, bias pre-sum) ----------------
__global__ __launch_bounds__(256) void k_prep(
    const float* __restrict__ tv_w, const float* __restrict__ tk_w,
    const float* __restrict__ tq_w, const float* __restrict__ l2_wih,
    const float* __restrict__ l2_bih, const float* __restrict__ l2_bhh,
    _Float16* __restrict__ w16, float* __restrict__ bsum)
{
    const int t = blockIdx.x * 256 + threadIdx.x;
    if (t < 4096)       w16[t] = (_Float16)tv_w[t];
    else if (t < 8192)  w16[t] = (_Float16)tk_w[t - 4096];
    else if (t < 12288) w16[t] = (_Float16)tq_w[t - 8192];
    else                w16[t] = (_Float16)l2_wih[t - 12288];
    if (t < 64) bsum[t] = l2_bih[t] + l2_bhh[t];
}

// ---------------- Kernel 1: feature attention, row-per-thread, parallel att ----------------
__global__ __launch_bounds__(128) void k_feat(
    const float* __restrict__ x,
    const float* __restrict__ fv_w, const float* __restrict__ fv_b,
    const float* __restrict__ fk_w, const float* __restrict__ fk_b,
    const float* __restrict__ fq_w, const float* __restrict__ fq_b,
    _Float16* __restrict__ fa16)
{
    __shared__ float xs[SS * DD], vs[SS * DD], ks[SS * DD], qs[SS * DD];
    __shared__ float att[DD * DD];
    __shared__ float wv[49], wk[49], wq[49];
    __shared__ float bv[DD], bk[DD], bq[DD];
    const int b = blockIdx.x, t = threadIdx.x;
    const float* xb = x + (size_t)b * SS * DD;

    for (int idx = t; idx < SS * DD; idx += 128) xs[idx] = xb[idx];
    if (t < 49) { wv[t] = fv_w[t]; wk[t] = fk_w[t]; wq[t] = fq_w[t]; }
    if (t < DD) { bv[t] = fv_b[t]; bk[t] = fk_b[t]; bq[t] = fq_b[t]; }
    __syncthreads();

    if (t < SS) {
        float xr[DD], vr[DD], kr[DD];
        #pragma unroll
        for (int i = 0; i < DD; i++) xr[i] = xs[t * DD + i];
        #pragma unroll
        for (int j = 0; j < DD; j++) {
            float a = bv[j];
            #pragma unroll
            for (int i = 0; i < DD; i++) a += xr[i] * wv[j * DD + i];
            vr[j] = a; vs[t * DD + j] = a;
        }
        #pragma unroll
        for (int j = 0; j < DD; j++) {
            float a = bk[j];
            #pragma unroll
            for (int i = 0; i < DD; i++) a += (xr[i] + vr[i]) * wk[j * DD + i];
            kr[j] = a; ks[t * DD + j] = a;
        }
        #pragma unroll
        for (int j = 0; j < DD; j++) {
            float a = bq[j];
            #pragma unroll
            for (int i = 0; i < DD; i++) a += (xr[i] + kr[i]) * wq[j * DD + i];
            qs[t * DD + j] = a;
        }
    }
    __syncthreads();

    if (t < 98) {
        const int g = t >> 1, l = t & 1;
        const int i = g / DD, j = g % DD;
        float a = 0.0f;
        for (int s = l; s < SS; s += 2) a += qs[s * DD + i] * ks[s * DD + j];
        a += __shfl_xor(a, 1);
        if (l == 0) att[g] = a;
    }
    __syncthreads();
    if (t < DD) {
        float m = -1e30f;
        #pragma unroll
        for (int j = 0; j < DD; j++) m = fmaxf(m, att[t * DD + j]);
        float e[DD]; float sum = 0.0f;
        #pragma unroll
        for (int j = 0; j < DD; j++) { e[j] = __expf(att[t * DD + j] - m); sum += e[j]; }
        float inv = frcp(sum);
        #pragma unroll
        for (int j = 0; j < DD; j++) att[t * DD + j] = e[j] * inv;
    }
    __syncthreads();

    if (t < SS) {
        float vr[DD];
        #pragma unroll
        for (int i = 0; i < DD; i++) vr[i] = vs[t * DD + i];
        f16x8 o;
        #pragma unroll
        for (int j = 0; j < DD; j++) {
            float a = xs[t * DD + j];
            #pragma unroll
            for (int i = 0; i < DD; i++) a += vr[i] * att[i * DD + j];
            o[j] = (_Float16)tanh_f(a);
        }
        o[7] = (_Float16)1.0f;
        *(f16x8*)(fa16 + (size_t)b * FASTR + t * 8) = o;
    }
}

// ---------------- Kernel 2: MFMA-batched bidirectional LSTM (R6 config: 16 batches, 256 blocks) ----------------
__global__ __launch_bounds__(256, 2) void k_bilstm(
    const _Float16* __restrict__ fa16,
    const float* __restrict__ wih_f, const float* __restrict__ whh_f,
    const float* __restrict__ bih_f, const float* __restrict__ bhh_f,
    const float* __restrict__ wih_b, const float* __restrict__ whh_b,
    const float* __restrict__ bih_b, const float* __restrict__ bhh_b,
    _Float16* __restrict__ hf, _Float16* __restrict__ hb)
{
    __shared__ __align__(16) _Float16 faS[16 * FASTR];   // [n][s*8+i], i=7 holds 1.0
    __shared__ __align__(16) _Float16 hS[2][16 * HST2];  // h dbuf: [n][unit]

    const int bx = blockIdx.x;
    const int bg = bx >> 1, dir = bx & 1;
    const int t = threadIdx.x, lane = t & 63, w = t >> 6;
    const int col = lane & 15, quad = lane >> 4;

    const float* wih = dir ? wih_b : wih_f;
    const float* whh = dir ? whh_b : whh_f;
    const float* bih = dir ? bih_b : bih_f;
    const float* bhh = dir ? bhh_b : bhh_f;
    _Float16* hout = dir ? hb : hf;

    for (int i = t; i < 2 * 16 * HST2 / 2; i += 256) ((unsigned int*)hS)[i] = 0u;

    f16x8 wh[4][2];
    f16x8 wi[4];
    #pragma unroll
    for (int gt = 0; gt < 4; gt++) {
        const int row = 16 * (w + 4 * gt) + col;
        wh[gt][0] = frag_from_f32(whh + row * HH + quad * 8);
        wh[gt][1] = frag_from_f32(whh + row * HH + 32 + quad * 8);
        f16x8 v;
        #pragma unroll
        for (int j = 0; j < 8; j++) v[j] = (_Float16)0.0f;
        if (quad == 0) {
            #pragma unroll
            for (int j = 0; j < DD; j++) v[j] = (_Float16)wih[row * DD + j];
            v[7] = (_Float16)(bih[row] + bhh[row]);
        }
        wi[gt] = v;
    }

    // vector-copy staging: fa16 already in faS layout
    const f16x8* fab = (const f16x8*)(fa16 + (size_t)(bg * 16) * FASTR);
    f16x8* faD = (f16x8*)faS;
    for (int i8 = t; i8 < 16 * FASTR / 8; i8 += 256) faD[i8] = fab[i8];
    __syncthreads();

    const int sstep = dir ? -HH : HH;
    _Float16* hp = hout + ((size_t)(bg * 16 + col)) * SS * HH
                 + (dir ? (SS - 1) : 0) * HH + 16 * w + quad * 4;

    const f32x4 ZC = {0.f, 0.f, 0.f, 0.f};
    float c0 = 0.f, c1 = 0.f, c2 = 0.f, c3 = 0.f;
    f16x4 hq;
    f32x4 gin[4];

    {
        const int s0 = dir ? (SS - 1) : 0;
        f16x8 faf;
        #pragma unroll
        for (int j = 0; j < 8; j++) faf[j] = (_Float16)0.0f;
        if (quad == 0) faf = *(const f16x8*)(&faS[col * FASTR + s0 * 8]);
        #pragma unroll
        for (int gt = 0; gt < 4; gt++)
            gin[gt] = __builtin_amdgcn_mfma_f32_16x16x32_f16(wi[gt], faf, ZC, 0, 0, 0);
    }

    for (int step = 0; step < SS; step++) {
        const int p = step & 1;

        if (step) {
            *(f16x4*)hp = hq;
            hp += sstep;
        }

        f16x8 h0 = *(const f16x8*)(&hS[p][col * HST2 + quad * 8]);
        f16x8 h1 = *(const f16x8*)(&hS[p][col * HST2 + 32 + quad * 8]);

        f32x4 g[4];
        #pragma unroll
        for (int gt = 0; gt < 4; gt++) {
            f32x4 acc = __builtin_amdgcn_mfma_f32_16x16x32_f16(wh[gt][0], h0, gin[gt], 0, 0, 0);
            acc = __builtin_amdgcn_mfma_f32_16x16x32_f16(wh[gt][1], h1, acc, 0, 0, 0);
            g[gt] = acc;
        }
        {
            float iv, fv, gv, ov, hv;
            iv = sigm(g[0][0]); fv = sigm(g[1][0]); gv = tanh_f(g[2][0]); ov = sigm(g[3][0]);
            c0 = fv * c0 + iv * gv; hv = ov * tanh_f(c0); hq[0] = (_Float16)hv;
            iv = sigm(g[0][1]); fv = sigm(g[1][1]); gv = tanh_f(g[2][1]); ov = sigm(g[3][1]);
            c1 = fv * c1 + iv * gv; hv = ov * tanh_f(c1); hq[1] = (_Float16)hv;
            iv = sigm(g[0][2]); fv = sigm(g[1][2]); gv = tanh_f(g[2][2]); ov = sigm(g[3][2]);
            c2 = fv * c2 + iv * gv; hv = ov * tanh_f(c2); hq[2] = (_Float16)hv;
            iv = sigm(g[0][3]); fv = sigm(g[1][3]); gv = tanh_f(g[2][3]); ov = sigm(g[3][3]);
            c3 = fv * c3 + iv * gv; hv = ov * tanh_f(c3); hq[3] = (_Float16)hv;
        }
        *(f16x4*)(&hS[1 - p][col * HST2 + 16 * w + quad * 4]) = hq;

        if (step + 1 < SS) {
            const int sn = dir ? (SS - 2 - step) : (step + 1);
            f16x8 faf;
            #pragma unroll
            for (int j = 0; j < 8; j++) faf[j] = (_Float16)0.0f;
            if (quad == 0) faf = *(const f16x8*)(&faS[col * FASTR + sn * 8]);
            #pragma unroll
            for (int gt = 0; gt < 4; gt++)
                gin[gt] = __builtin_amdgcn_mfma_f32_16x16x32_f16(wi[gt], faf, ZC, 0, 0, 0);
        }
        __syncthreads();
    }
    *(f16x4*)hp = hq;
}

// ---------------- Kernel 3: temporal attention FUSED with lstm2+fc ----------------
// Final projection writes gates to LDS (dead q/tk region); wave 0 runs the 96-step
// H2=16 recurrence from LDS; fc spread over all 512 threads writes `out` directly.
// Kills the k_lstm2 launch and the 50MB xg2 HBM round-trip.
__global__ __launch_bounds__(512, 1) void k_attn(
    const _Float16* __restrict__ hf, const _Float16* __restrict__ hb,
    const float* __restrict__ tv_b, const float* __restrict__ tk_b,
    const float* __restrict__ tq_b,
    const _Float16* __restrict__ w16, const float* __restrict__ bsum,
    const float* __restrict__ l2_whh,
    const float* __restrict__ fc_w, const float* __restrict__ fc_b,
    float* __restrict__ out)
{
    __shared__ __align__(16) _Float16 loB[SS * LO_ST];       // lo -> 'to' -> h-history
    __shared__ __align__(16) _Float16 tvT[HH * TV_ST];       // tv^T[d][P]
    __shared__ __align__(16) _Float16 uQK[2 * SS * QK_ST];   // q|tk -> p -> gates
    __shared__ float fcwS[DD * H2];
    __shared__ float fcbS[DD];
    _Float16* qS  = uQK;
    _Float16* tkS = uQK + SS * QK_ST;
    _Float16* pS  = uQK;   // stride P_ST, 96x96 used
    _Float16* gS  = uQK;   // gates [s][64], stride 64 (12,288B) - after p dies

    const int b = blockIdx.x, t = threadIdx.x;
    const int lane = t & 63, w = t >> 6;
    const int col = lane & 15, quad = lane >> 4;

    // ---- hoisted global loads: one deep burst ----
    f16x8 wf0[9], wf1[9]; float bj9[9];
    #pragma unroll
    for (int i = 0; i < 9; i++) {
        const int flat = w + 8 * i;
        const int proj = flat / 24, rem = flat % 24;
        const int nt = rem & 3;
        const int j = 16 * nt + col;
        const _Float16* wp = w16 + proj * 4096 + j * 64 + quad * 8;
        wf0[i] = *(const f16x8*)wp;
        wf1[i] = *(const f16x8*)(wp + 32);
        const float* bvec = (proj == 0) ? tv_b : (proj == 1) ? tk_b : tq_b;
        bj9[i] = bvec[j];
    }
    f16x8 l2f0[3], l2f1[3]; float bg3[3];
    #pragma unroll
    for (int i = 0; i < 3; i++) {
        const int flat = w + 8 * i;
        const int nt = flat & 3;
        const int g = 16 * nt + col;
        const _Float16* wp = w16 + 12288 + g * 64 + quad * 8;
        l2f0[i] = *(const f16x8*)wp;
        l2f1[i] = *(const f16x8*)(wp + 32);
        bg3[i] = bsum[g];
    }
    // lstm2 recurrence weights (wave 0 only uses them; loaded by t<64)
    float whr[H2];
    if (t < 64) {
        #pragma unroll
        for (int j = 0; j < H2; j++) whr[j] = l2_whh[lane * H2 + j];
    }
    if (t < DD * H2) fcwS[t] = fc_w[t];
    if (t < DD)      fcbS[t] = fc_b[t];

    const _Float16* hfp = hf + (size_t)b * SS * HH;
    const _Float16* hbp = hb + (size_t)b * SS * HH;
    for (int g8 = t; g8 < 768; g8 += 512) {
        f16x8 va = *(const f16x8*)(hfp + g8 * 8);
        f16x8 vb = *(const f16x8*)(hbp + g8 * 8);
        int s = g8 >> 3, d = (g8 & 7) * 8;
        f16x8 r;
        #pragma unroll
        for (int j = 0; j < 8; j++) r[j] = (_Float16)(0.5f * ((float)va[j] + (float)vb[j]));
        *(f16x8*)(&loB[s * LO_ST + d]) = r;
    }
    __syncthreads();

    // projections
    #pragma unroll
    for (int i = 0; i < 9; i++) {
        const int flat = w + 8 * i;
        const int proj = flat / 24, rem = flat % 24;
        const int mt = rem >> 2, nt = rem & 3;
        const int j = 16 * nt + col;
        f32x4 acc = {0.f, 0.f, 0.f, 0.f};
        {
            f16x8 a0 = *(const f16x8*)(&loB[(16 * mt + col) * LO_ST + quad * 8]);
            f16x8 a1 = *(const f16x8*)(&loB[(16 * mt + col) * LO_ST + 32 + quad * 8]);
            acc = __builtin_amdgcn_mfma_f32_16x16x32_f16(a0, wf0[i], acc, 0, 0, 0);
            acc = __builtin_amdgcn_mfma_f32_16x16x32_f16(a1, wf1[i], acc, 0, 0, 0);
        }
        const float bj = bj9[i];
        #pragma unroll
        for (int r = 0; r < 4; r++) {
            const float v = acc[r] + bj;
            const int row = 16 * mt + quad * 4 + r;
            if (proj == 0)      tvT[j * TV_ST + row] = (_Float16)v;
            else if (proj == 1) tkS[row * QK_ST + j] = (_Float16)v;
            else                qS[row * QK_ST + j]  = (_Float16)v;
        }
    }
    __syncthreads();

    // scores into registers (q/tk die here)
    f32x4 sc[6];
    const int mt = w;
    if (w < 6) {
        f16x8 aq0 = ld2x4(qS + (16 * mt + col) * QK_ST + quad * 8);
        f16x8 aq1 = ld2x4(qS + (16 * mt + col) * QK_ST + 32 + quad * 8);
        #pragma unroll
        for (int nt = 0; nt < 6; nt++) {
            f32x4 acc = {0.f, 0.f, 0.f, 0.f};
            f16x8 b0 = ld2x4(tkS + (16 * nt + col) * QK_ST + quad * 8);
            f16x8 b1 = ld2x4(tkS + (16 * nt + col) * QK_ST + 32 + quad * 8);
            acc = __builtin_amdgcn_mfma_f32_16x16x32_f16(aq0, b0, acc, 0, 0, 0);
            acc = __builtin_amdgcn_mfma_f32_16x16x32_f16(aq1, b1, acc, 0, 0, 0);
            sc[nt] = acc;
        }
    }
    __syncthreads();   // all q/tk reads complete before p overlays them

    if (w < 6) {
        #pragma unroll
        for (int r = 0; r < 4; r++) {
            float m = sc[0][r];
            #pragma unroll
            for (int nt = 1; nt < 6; nt++) m = fmaxf(m, sc[nt][r]);
            #pragma unroll
            for (int o = 1; o < 16; o <<= 1) m = fmaxf(m, __shfl_xor(m, o));
            float e[6]; float sum = 0.0f;
            #pragma unroll
            for (int nt = 0; nt < 6; nt++) { e[nt] = __expf(sc[nt][r] - m); sum += e[nt]; }
            #pragma unroll
            for (int o = 1; o < 16; o <<= 1) sum += __shfl_xor(sum, o);
            const float inv = frcp(sum);
            const int row = 16 * mt + quad * 4 + r;
            #pragma unroll
            for (int nt = 0; nt < 6; nt++)
                pS[row * P_ST + 16 * nt + col] = (_Float16)(e[nt] * inv);
        }
        f16x8 pa0 = *(const f16x8*)(pS + (16 * mt + col) * P_ST + quad * 8);
        f16x8 pa1 = *(const f16x8*)(pS + (16 * mt + col) * P_ST + 32 + quad * 8);
        f16x8 pa2 = *(const f16x8*)(pS + (16 * mt + col) * P_ST + 64 + quad * 8);
        #pragma unroll
        for (int nt = 0; nt < 4; nt++) {
            f32x4 acc = {0.f, 0.f, 0.f, 0.f};
            const _Float16* tvrow = tvT + (16 * nt + col) * TV_ST;
            acc = __builtin_amdgcn_mfma_f32_16x16x32_f16(pa0, *(const f16x8*)(tvrow + quad * 8), acc, 0, 0, 0);
            acc = __builtin_amdgcn_mfma_f32_16x16x32_f16(pa1, *(const f16x8*)(tvrow + 32 + quad * 8), acc, 0, 0, 0);
            acc = __builtin_amdgcn_mfma_f32_16x16x32_f16(pa2, *(const f16x8*)(tvrow + 64 + quad * 8), acc, 0, 0, 0);
            #pragma unroll
            for (int r = 0; r < 4; r++)
                loB[(16 * mt + quad * 4 + r) * LO_ST + 16 * nt + col] = (_Float16)tanh_f(acc[r]);
        }
    }
    __syncthreads();

    // lstm2 input gates -> LDS (gS overlays dead p region; barrier above guards WAR)
    #pragma unroll
    for (int i = 0; i < 3; i++) {
        const int flat = w + 8 * i;
        const int mt2 = flat >> 2, nt = flat & 3;
        const int g = 16 * nt + col;
        f32x4 acc = {0.f, 0.f, 0.f, 0.f};
        {
            f16x8 a0 = *(const f16x8*)(&loB[(16 * mt2 + col) * LO_ST + quad * 8]);
            f16x8 a1 = *(const f16x8*)(&loB[(16 * mt2 + col) * LO_ST + 32 + quad * 8]);
            acc = __builtin_amdgcn_mfma_f32_16x16x32_f16(a0, l2f0[i], acc, 0, 0, 0);
            acc = __builtin_amdgcn_mfma_f32_16x16x32_f16(a1, l2f1[i], acc, 0, 0, 0);
        }
        const float bg2 = bg3[i];
        #pragma unroll
        for (int r = 0; r < 4; r++) {
            const int row = 16 * mt2 + quad * 4 + r;
            gS[row * HH + g] = (_Float16)(acc[r] + bg2);
        }
    }
    __syncthreads();

    // lstm2 recurrence: wave 0 only (lane = gate-row over 64 = 4 gates x 16 units).
    // h history written into loB region (free after gate MFMAs + barrier).
    _Float16* hh = loB;   // [s][16]
    if (t < 64) {
        const int u16 = lane & 15;
        float h = 0.0f, c = 0.0f;
        for (int s = 0; s < SS; s++) {
            float a0 = (float)gS[s * HH + lane], a1 = 0.0f, a2 = 0.0f, a3 = 0.0f;
            #pragma unroll
            for (int j = 0; j < H2; j += 4) {
                a0 += rl(h, j)     * whr[j];
                a1 += rl(h, j + 1) * whr[j + 1];
                a2 += rl(h, j + 2) * whr[j + 2];
                a3 += rl(h, j + 3) * whr[j + 3];
            }
            float a = (a0 + a1) + (a2 + a3);
            float iv = __shfl(a, u16);
            float fv = __shfl(a, H2 + u16);
            float gv = __shfl(a, 2 * H2 + u16);
            float ov = __shfl(a, 3 * H2 + u16);
            c = sigm(fv) * c + sigm(iv) * tanh_f(gv);
            h = sigm(ov) * tanh_f(c);
            if (lane < H2) hh[s * H2 + lane] = (_Float16)h;
        }
    }
    __syncthreads();

    // fc: 672 outputs over 512 threads
    for (int idx = t; idx < SS * DD; idx += 512) {
        const int s = idx / DD, d = idx % DD;
        float a = fcbS[d];
        #pragma unroll
        for (int j = 0; j < H2; j++) a += (float)hh[s * H2 + j] * fcwS[d * H2 + j];
        out[((size_t)b * SS + s) * DD + d] = a;
    }
}

extern "C" void kernel_launch(void* const* d_in, const int* in_sizes, int n_in,
                              void* d_out, int out_size, void* d_ws, size_t ws_size,
                              hipStream_t stream) {
    const float* x     = (const float*)d_in[0];
    const float* fv_w  = (const float*)d_in[1];
    const float* fv_b  = (const float*)d_in[2];
    const float* fk_w  = (const float*)d_in[3];
    const float* fk_b  = (const float*)d_in[4];
    const float* fq_w  = (const float*)d_in[5];
    const float* fq_b  = (const float*)d_in[6];
    const float* l1f_wih = (const float*)d_in[7];
    const float* l1f_whh = (const float*)d_in[8];
    const float* l1f_bih = (const float*)d_in[9];
    const float* l1f_bhh = (const float*)d_in[10];
    const float* l1b_wih = (const float*)d_in[11];
    const float* l1b_whh = (const float*)d_in[12];
    const float* l1b_bih = (const float*)d_in[13];
    const float* l1b_bhh = (const float*)d_in[14];
    const float* tv_w  = (const float*)d_in[15];
    const float* tv_b  = (const float*)d_in[16];
    const float* tk_w  = (const float*)d_in[17];
    const float* tk_b  = (const float*)d_in[18];
    const float* tq_w  = (const float*)d_in[19];
    const float* tq_b  = (const float*)d_in[20];
    const float* l2_wih = (const float*)d_in[21];
    const float* l2_whh = (const float*)d_in[22];
    const float* l2_bih = (const float*)d_in[23];
    const float* l2_bhh = (const float*)d_in[24];
    const float* fc_w  = (const float*)d_in[25];
    const float* fc_b  = (const float*)d_in[26];

    _Float16* fa16 = (_Float16*)d_ws;                      // B*FASTR f16 (3.18MB)
    _Float16* hf = fa16 + (size_t)BB * FASTR;              // B*S*H f16 (25.2MB)
    _Float16* hb = hf + (size_t)BB * SS * HH;              // B*S*H f16 (25.2MB)
    _Float16* w16 = hb + (size_t)BB * SS * HH;             // 16384 f16 (32KB)
    float* bsum = (float*)(w16 + 16384);                   // 64 f32

    k_prep<<<64, 256, 0, stream>>>(tv_w, tk_w, tq_w, l2_wih, l2_bih, l2_bhh, w16, bsum);
    k_feat<<<BB, 128, 0, stream>>>(x, fv_w, fv_b, fk_w, fk_b, fq_w, fq_b, fa16);
    k_bilstm<<<256, 256, 0, stream>>>(fa16,
        l1f_wih, l1f_whh, l1f_bih, l1f_bhh,
        l1b_wih, l1b_whh, l1b_bih, l1b_bhh, hf, hb);
    k_attn<<<BB, 512, 0, stream>>>(hf, hb,
        tv_b, tk_b, tq_b, w16, bsum,
        l2_whh, fc_w, fc_b, (float*)d_out);
}

// Round 9
// 245.231 us; speedup vs baseline: 1.7442x; 1.7442x over previous
//
#include <hip/hip_runtime.h>
#include <math.h>

#define BB 2048
#define SS 96
#define DD 7
#define HH 64
#define H2 16
#define FASTR 776  // fa16 / faS row stride (f16): 97*16B
#define HST2 72    // k_bilstm h dbuf row stride (f16)
#define LO_ST 72   // k_attn loB stride (f16)
#define QK_ST 68   // k_attn q/tk stride (f16), b64-aligned
#define TV_ST 104  // k_attn tvT stride (f16)
#define P_ST 104   // k_attn p stride (f16), overlays q+tk region
#define HSB 20     // k_lstm2 h-history stride (f16)

typedef _Float16 f16x8 __attribute__((ext_vector_type(8)));
typedef _Float16 f16x4 __attribute__((ext_vector_type(4)));
typedef float f32x4 __attribute__((ext_vector_type(4)));

// Fast rcp-based nonlinearities (no -ffast-math: IEEE div = ~11 instrs).
__device__ __forceinline__ float frcp(float x) { return __builtin_amdgcn_rcpf(x); }
__device__ __forceinline__ float sigm(float x) { return frcp(1.0f + __expf(-x)); }
__device__ __forceinline__ float tanh_f(float x) { return 1.0f - 2.0f * frcp(__expf(2.0f * x) + 1.0f); }
__device__ __forceinline__ float rl(float v, int l) {
    return __int_as_float(__builtin_amdgcn_readlane(__float_as_int(v), l));
}
// load 8 consecutive fp32 (16B-aligned) -> f16x8 fragment
__device__ __forceinline__ f16x8 frag_from_f32(const float* base) {
    const float4* p = (const float4*)base;
    float4 a = p[0], b = p[1];
    f16x8 r;
    r[0] = (_Float16)a.x; r[1] = (_Float16)a.y; r[2] = (_Float16)a.z; r[3] = (_Float16)a.w;
    r[4] = (_Float16)b.x; r[5] = (_Float16)b.y; r[6] = (_Float16)b.z; r[7] = (_Float16)b.w;
    return r;
}
// two ds_read_b64 -> f16x8 (for 8B-aligned strides)
__device__ __forceinline__ f16x8 ld2x4(const _Float16* p) {
    f16x4 a = *(const f16x4*)p;
    f16x4 b = *(const f16x4*)(p + 4);
    f16x8 r;
    r[0]=a[0]; r[1]=a[1]; r[2]=a[2]; r[3]=a[3];
    r[4]=b[0]; r[5]=b[1]; r[6]=b[2]; r[7]=b[3];
    return r;
}

// ---------------- Kernel 1: feature attention (+ folded weight prep) ----------------
// Each block also converts 8 elements of the attn/l2 weights to f16 (k_prep folded in);
// stream ordering (feat -> bilstm -> attn) guarantees visibility before k_attn reads.
__global__ __launch_bounds__(128) void k_feat(
    const float* __restrict__ x,
    const float* __restrict__ fv_w, const float* __restrict__ fv_b,
    const float* __restrict__ fk_w, const float* __restrict__ fk_b,
    const float* __restrict__ fq_w, const float* __restrict__ fq_b,
    const float* __restrict__ tv_w, const float* __restrict__ tk_w,
    const float* __restrict__ tq_w, const float* __restrict__ l2_wih,
    const float* __restrict__ l2_bih, const float* __restrict__ l2_bhh,
    _Float16* __restrict__ w16, float* __restrict__ bsum,
    _Float16* __restrict__ fa16)
{
    __shared__ float xs[SS * DD], vs[SS * DD], ks[SS * DD], qs[SS * DD];
    __shared__ float att[DD * DD];
    __shared__ float wv[49], wk[49], wq[49];
    __shared__ float bv[DD], bk[DD], bq[DD];
    const int b = blockIdx.x, t = threadIdx.x;
    const float* xb = x + (size_t)b * SS * DD;

    // folded prep: 8 weight elements per block
    if (t < 8) {
        const int idx = b * 8 + t;
        if (idx < 4096)       w16[idx] = (_Float16)tv_w[idx];
        else if (idx < 8192)  w16[idx] = (_Float16)tk_w[idx - 4096];
        else if (idx < 12288) w16[idx] = (_Float16)tq_w[idx - 8192];
        else                  w16[idx] = (_Float16)l2_wih[idx - 12288];
    }
    if (b == 0 && t >= 8 && t < 72) {
        const int j = t - 8;
        bsum[j] = l2_bih[j] + l2_bhh[j];
    }

    for (int idx = t; idx < SS * DD; idx += 128) xs[idx] = xb[idx];
    if (t < 49) { wv[t] = fv_w[t]; wk[t] = fk_w[t]; wq[t] = fq_w[t]; }
    if (t < DD) { bv[t] = fv_b[t]; bk[t] = fk_b[t]; bq[t] = fq_b[t]; }
    __syncthreads();

    if (t < SS) {
        float xr[DD], vr[DD], kr[DD];
        #pragma unroll
        for (int i = 0; i < DD; i++) xr[i] = xs[t * DD + i];
        #pragma unroll
        for (int j = 0; j < DD; j++) {
            float a = bv[j];
            #pragma unroll
            for (int i = 0; i < DD; i++) a += xr[i] * wv[j * DD + i];
            vr[j] = a; vs[t * DD + j] = a;
        }
        #pragma unroll
        for (int j = 0; j < DD; j++) {
            float a = bk[j];
            #pragma unroll
            for (int i = 0; i < DD; i++) a += (xr[i] + vr[i]) * wk[j * DD + i];
            kr[j] = a; ks[t * DD + j] = a;
        }
        #pragma unroll
        for (int j = 0; j < DD; j++) {
            float a = bq[j];
            #pragma unroll
            for (int i = 0; i < DD; i++) a += (xr[i] + kr[i]) * wq[j * DD + i];
            qs[t * DD + j] = a;
        }
    }
    __syncthreads();

    // att[i][j]: 2 lanes per (i,j), 4 independent accumulators (chain 48 -> 12 deep)
    if (t < 98) {
        const int g = t >> 1, l = t & 1;
        const int i = g / DD, j = g % DD;
        float a0 = 0.f, a1 = 0.f, a2 = 0.f, a3 = 0.f;
        for (int s = l; s + 6 < SS; s += 8) {
            a0 += qs[s * DD + i]       * ks[s * DD + j];
            a1 += qs[(s + 2) * DD + i] * ks[(s + 2) * DD + j];
            a2 += qs[(s + 4) * DD + i] * ks[(s + 4) * DD + j];
            a3 += qs[(s + 6) * DD + i] * ks[(s + 6) * DD + j];
        }
        float a = (a0 + a1) + (a2 + a3);
        a += __shfl_xor(a, 1);
        if (l == 0) att[g] = a;
    }
    __syncthreads();
    if (t < DD) {
        float m = -1e30f;
        #pragma unroll
        for (int j = 0; j < DD; j++) m = fmaxf(m, att[t * DD + j]);
        float e[DD]; float sum = 0.0f;
        #pragma unroll
        for (int j = 0; j < DD; j++) { e[j] = __expf(att[t * DD + j] - m); sum += e[j]; }
        float inv = frcp(sum);
        #pragma unroll
        for (int j = 0; j < DD; j++) att[t * DD + j] = e[j] * inv;
    }
    __syncthreads();

    if (t < SS) {
        float vr[DD];
        #pragma unroll
        for (int i = 0; i < DD; i++) vr[i] = vs[t * DD + i];
        f16x8 o;
        #pragma unroll
        for (int j = 0; j < DD; j++) {
            float a = xs[t * DD + j];
            #pragma unroll
            for (int i = 0; i < DD; i++) a += vr[i] * att[i * DD + j];
            o[j] = (_Float16)tanh_f(a);
        }
        o[7] = (_Float16)1.0f;
        *(f16x8*)(fa16 + (size_t)b * FASTR + t * 8) = o;
    }
}

// ---------------- Kernel 2: MFMA-batched bidirectional LSTM (R6 version, best known) ----------------
__global__ __launch_bounds__(256, 2) void k_bilstm(
    const _Float16* __restrict__ fa16,
    const float* __restrict__ wih_f, const float* __restrict__ whh_f,
    const float* __restrict__ bih_f, const float* __restrict__ bhh_f,
    const float* __restrict__ wih_b, const float* __restrict__ whh_b,
    const float* __restrict__ bih_b, const float* __restrict__ bhh_b,
    _Float16* __restrict__ hf, _Float16* __restrict__ hb)
{
    __shared__ __align__(16) _Float16 faS[16 * FASTR];   // [n][s*8+i], i=7 holds 1.0
    __shared__ __align__(16) _Float16 hS[2][16 * HST2];  // h dbuf: [n][unit]

    const int bx = blockIdx.x;
    const int bg = bx >> 1, dir = bx & 1;
    const int t = threadIdx.x, lane = t & 63, w = t >> 6;
    const int col = lane & 15, quad = lane >> 4;

    const float* wih = dir ? wih_b : wih_f;
    const float* whh = dir ? whh_b : whh_f;
    const float* bih = dir ? bih_b : bih_f;
    const float* bhh = dir ? bhh_b : bhh_f;
    _Float16* hout = dir ? hb : hf;

    for (int i = t; i < 2 * 16 * HST2 / 2; i += 256) ((unsigned int*)hS)[i] = 0u;

    f16x8 wh[4][2];
    f16x8 wi[4];
    #pragma unroll
    for (int gt = 0; gt < 4; gt++) {
        const int row = 16 * (w + 4 * gt) + col;
        wh[gt][0] = frag_from_f32(whh + row * HH + quad * 8);
        wh[gt][1] = frag_from_f32(whh + row * HH + 32 + quad * 8);
        f16x8 v;
        #pragma unroll
        for (int j = 0; j < 8; j++) v[j] = (_Float16)0.0f;
        if (quad == 0) {
            #pragma unroll
            for (int j = 0; j < DD; j++) v[j] = (_Float16)wih[row * DD + j];
            v[7] = (_Float16)(bih[row] + bhh[row]);
        }
        wi[gt] = v;
    }

    // vector-copy staging: fa16 already in faS layout
    const f16x8* fab = (const f16x8*)(fa16 + (size_t)(bg * 16) * FASTR);
    f16x8* faD = (f16x8*)faS;
    for (int i8 = t; i8 < 16 * FASTR / 8; i8 += 256) faD[i8] = fab[i8];
    __syncthreads();

    const int sstep = dir ? -HH : HH;
    _Float16* hp = hout + ((size_t)(bg * 16 + col)) * SS * HH
                 + (dir ? (SS - 1) : 0) * HH + 16 * w + quad * 4;

    const f32x4 ZC = {0.f, 0.f, 0.f, 0.f};
    float c0 = 0.f, c1 = 0.f, c2 = 0.f, c3 = 0.f;
    f16x4 hq;
    f32x4 gin[4];

    {
        const int s0 = dir ? (SS - 1) : 0;
        f16x8 faf;
        #pragma unroll
        for (int j = 0; j < 8; j++) faf[j] = (_Float16)0.0f;
        if (quad == 0) faf = *(const f16x8*)(&faS[col * FASTR + s0 * 8]);
        #pragma unroll
        for (int gt = 0; gt < 4; gt++)
            gin[gt] = __builtin_amdgcn_mfma_f32_16x16x32_f16(wi[gt], faf, ZC, 0, 0, 0);
    }

    for (int step = 0; step < SS; step++) {
        const int p = step & 1;

        if (step) {
            *(f16x4*)hp = hq;
            hp += sstep;
        }

        f16x8 h0 = *(const f16x8*)(&hS[p][col * HST2 + quad * 8]);
        f16x8 h1 = *(const f16x8*)(&hS[p][col * HST2 + 32 + quad * 8]);

        f32x4 g[4];
        #pragma unroll
        for (int gt = 0; gt < 4; gt++) {
            f32x4 acc = __builtin_amdgcn_mfma_f32_16x16x32_f16(wh[gt][0], h0, gin[gt], 0, 0, 0);
            acc = __builtin_amdgcn_mfma_f32_16x16x32_f16(wh[gt][1], h1, acc, 0, 0, 0);
            g[gt] = acc;
        }
        {
            float iv, fv, gv, ov, hv;
            iv = sigm(g[0][0]); fv = sigm(g[1][0]); gv = tanh_f(g[2][0]); ov = sigm(g[3][0]);
            c0 = fv * c0 + iv * gv; hv = ov * tanh_f(c0); hq[0] = (_Float16)hv;
            iv = sigm(g[0][1]); fv = sigm(g[1][1]); gv = tanh_f(g[2][1]); ov = sigm(g[3][1]);
            c1 = fv * c1 + iv * gv; hv = ov * tanh_f(c1); hq[1] = (_Float16)hv;
            iv = sigm(g[0][2]); fv = sigm(g[1][2]); gv = tanh_f(g[2][2]); ov = sigm(g[3][2]);
            c2 = fv * c2 + iv * gv; hv = ov * tanh_f(c2); hq[2] = (_Float16)hv;
            iv = sigm(g[0][3]); fv = sigm(g[1][3]); gv = tanh_f(g[2][3]); ov = sigm(g[3][3]);
            c3 = fv * c3 + iv * gv; hv = ov * tanh_f(c3); hq[3] = (_Float16)hv;
        }
        *(f16x4*)(&hS[1 - p][col * HST2 + 16 * w + quad * 4]) = hq;

        if (step + 1 < SS) {
            const int sn = dir ? (SS - 2 - step) : (step + 1);
            f16x8 faf;
            #pragma unroll
            for (int j = 0; j < 8; j++) faf[j] = (_Float16)0.0f;
            if (quad == 0) faf = *(const f16x8*)(&faS[col * FASTR + sn * 8]);
            #pragma unroll
            for (int gt = 0; gt < 4; gt++)
                gin[gt] = __builtin_amdgcn_mfma_f32_16x16x32_f16(wi[gt], faf, ZC, 0, 0, 0);
        }
        __syncthreads();
    }
    *(f16x4*)hp = hq;
}

// ---------------- Kernel 3: temporal attention (R6 version + coalesced xg2 stores) ----------------
__global__ __launch_bounds__(512, 1) void k_attn(
    const _Float16* __restrict__ hf, const _Float16* __restrict__ hb,
    const float* __restrict__ tv_b, const float* __restrict__ tk_b,
    const float* __restrict__ tq_b,
    const _Float16* __restrict__ w16, const float* __restrict__ bsum,
    _Float16* __restrict__ xg2)
{
    __shared__ __align__(16) _Float16 loB[SS * LO_ST];       // lo -> 'to'
    __shared__ __align__(16) _Float16 tvT[HH * TV_ST];       // tv^T[d][P]
    __shared__ __align__(16) _Float16 uQK[2 * SS * QK_ST];   // q|tk -> p -> gates
    _Float16* qS  = uQK;
    _Float16* tkS = uQK + SS * QK_ST;
    _Float16* pS  = uQK;   // stride P_ST, 96x96 used
    _Float16* gS  = uQK;   // gates [s][64] (12,288B), after p dies

    const int b = blockIdx.x, t = threadIdx.x;
    const int lane = t & 63, w = t >> 6;
    const int col = lane & 15, quad = lane >> 4;

    // ---- hoisted weight fragments (one deep global-load burst) ----
    f16x8 wf0[9], wf1[9]; float bj9[9];
    #pragma unroll
    for (int i = 0; i < 9; i++) {
        const int flat = w + 8 * i;
        const int proj = flat / 24, rem = flat % 24;
        const int nt = rem & 3;
        const int j = 16 * nt + col;
        const _Float16* wp = w16 + proj * 4096 + j * 64 + quad * 8;
        wf0[i] = *(const f16x8*)wp;
        wf1[i] = *(const f16x8*)(wp + 32);
        const float* bvec = (proj == 0) ? tv_b : (proj == 1) ? tk_b : tq_b;
        bj9[i] = bvec[j];
    }
    f16x8 l2f0[3], l2f1[3]; float bg3[3];
    #pragma unroll
    for (int i = 0; i < 3; i++) {
        const int flat = w + 8 * i;
        const int nt = flat & 3;
        const int g = 16 * nt + col;
        const _Float16* wp = w16 + 12288 + g * 64 + quad * 8;
        l2f0[i] = *(const f16x8*)wp;
        l2f1[i] = *(const f16x8*)(wp + 32);
        bg3[i] = bsum[g];
    }

    const _Float16* hfp = hf + (size_t)b * SS * HH;
    const _Float16* hbp = hb + (size_t)b * SS * HH;
    for (int g8 = t; g8 < 768; g8 += 512) {
        f16x8 va = *(const f16x8*)(hfp + g8 * 8);
        f16x8 vb = *(const f16x8*)(hbp + g8 * 8);
        int s = g8 >> 3, d = (g8 & 7) * 8;
        f16x8 r;
        #pragma unroll
        for (int j = 0; j < 8; j++) r[j] = (_Float16)(0.5f * ((float)va[j] + (float)vb[j]));
        *(f16x8*)(&loB[s * LO_ST + d]) = r;
    }
    __syncthreads();

    // projections
    #pragma unroll
    for (int i = 0; i < 9; i++) {
        const int flat = w + 8 * i;
        const int proj = flat / 24, rem = flat % 24;
        const int mt = rem >> 2, nt = rem & 3;
        const int j = 16 * nt + col;
        f32x4 acc = {0.f, 0.f, 0.f, 0.f};
        {
            f16x8 a0 = *(const f16x8*)(&loB[(16 * mt + col) * LO_ST + quad * 8]);
            f16x8 a1 = *(const f16x8*)(&loB[(16 * mt + col) * LO_ST + 32 + quad * 8]);
            acc = __builtin_amdgcn_mfma_f32_16x16x32_f16(a0, wf0[i], acc, 0, 0, 0);
            acc = __builtin_amdgcn_mfma_f32_16x16x32_f16(a1, wf1[i], acc, 0, 0, 0);
        }
        const float bj = bj9[i];
        #pragma unroll
        for (int r = 0; r < 4; r++) {
            const float v = acc[r] + bj;
            const int row = 16 * mt + quad * 4 + r;
            if (proj == 0)      tvT[j * TV_ST + row] = (_Float16)v;
            else if (proj == 1) tkS[row * QK_ST + j] = (_Float16)v;
            else                qS[row * QK_ST + j]  = (_Float16)v;
        }
    }
    __syncthreads();

    // scores into registers (q/tk die here)
    f32x4 sc[6];
    const int mt = w;
    if (w < 6) {
        f16x8 aq0 = ld2x4(qS + (16 * mt + col) * QK_ST + quad * 8);
        f16x8 aq1 = ld2x4(qS + (16 * mt + col) * QK_ST + 32 + quad * 8);
        #pragma unroll
        for (int nt = 0; nt < 6; nt++) {
            f32x4 acc = {0.f, 0.f, 0.f, 0.f};
            f16x8 b0 = ld2x4(tkS + (16 * nt + col) * QK_ST + quad * 8);
            f16x8 b1 = ld2x4(tkS + (16 * nt + col) * QK_ST + 32 + quad * 8);
            acc = __builtin_amdgcn_mfma_f32_16x16x32_f16(aq0, b0, acc, 0, 0, 0);
            acc = __builtin_amdgcn_mfma_f32_16x16x32_f16(aq1, b1, acc, 0, 0, 0);
            sc[nt] = acc;
        }
    }
    __syncthreads();   // all q/tk reads complete before p overlays them

    if (w < 6) {
        #pragma unroll
        for (int r = 0; r < 4; r++) {
            float m = sc[0][r];
            #pragma unroll
            for (int nt = 1; nt < 6; nt++) m = fmaxf(m, sc[nt][r]);
            #pragma unroll
            for (int o = 1; o < 16; o <<= 1) m = fmaxf(m, __shfl_xor(m, o));
            float e[6]; float sum = 0.0f;
            #pragma unroll
            for (int nt = 0; nt < 6; nt++) { e[nt] = __expf(sc[nt][r] - m); sum += e[nt]; }
            #pragma unroll
            for (int o = 1; o < 16; o <<= 1) sum += __shfl_xor(sum, o);
            const float inv = frcp(sum);
            const int row = 16 * mt + quad * 4 + r;
            #pragma unroll
            for (int nt = 0; nt < 6; nt++)
                pS[row * P_ST + 16 * nt + col] = (_Float16)(e[nt] * inv);
        }
        f16x8 pa0 = *(const f16x8*)(pS + (16 * mt + col) * P_ST + quad * 8);
        f16x8 pa1 = *(const f16x8*)(pS + (16 * mt + col) * P_ST + 32 + quad * 8);
        f16x8 pa2 = *(const f16x8*)(pS + (16 * mt + col) * P_ST + 64 + quad * 8);
        #pragma unroll
        for (int nt = 0; nt < 4; nt++) {
            f32x4 acc = {0.f, 0.f, 0.f, 0.f};
            const _Float16* tvrow = tvT + (16 * nt + col) * TV_ST;
            acc = __builtin_amdgcn_mfma_f32_16x16x32_f16(pa0, *(const f16x8*)(tvrow + quad * 8), acc, 0, 0, 0);
            acc = __builtin_amdgcn_mfma_f32_16x16x32_f16(pa1, *(const f16x8*)(tvrow + 32 + quad * 8), acc, 0, 0, 0);
            acc = __builtin_amdgcn_mfma_f32_16x16x32_f16(pa2, *(const f16x8*)(tvrow + 64 + quad * 8), acc, 0, 0, 0);
            #pragma unroll
            for (int r = 0; r < 4; r++)
                loB[(16 * mt + quad * 4 + r) * LO_ST + 16 * nt + col] = (_Float16)tanh_f(acc[r]);
        }
    }
    __syncthreads();

    // gate MFMAs -> LDS (gS overlays dead p region), then one coalesced vector copy
    #pragma unroll
    for (int i = 0; i < 3; i++) {
        const int flat = w + 8 * i;
        const int mt2 = flat >> 2, nt = flat & 3;
        const int g = 16 * nt + col;
        f32x4 acc = {0.f, 0.f, 0.f, 0.f};
        {
            f16x8 a0 = *(const f16x8*)(&loB[(16 * mt2 + col) * LO_ST + quad * 8]);
            f16x8 a1 = *(const f16x8*)(&loB[(16 * mt2 + col) * LO_ST + 32 + quad * 8]);
            acc = __builtin_amdgcn_mfma_f32_16x16x32_f16(a0, l2f0[i], acc, 0, 0, 0);
            acc = __builtin_amdgcn_mfma_f32_16x16x32_f16(a1, l2f1[i], acc, 0, 0, 0);
        }
        const float bg2 = bg3[i];
        #pragma unroll
        for (int r = 0; r < 4; r++) {
            const int row = 16 * mt2 + quad * 4 + r;
            gS[row * HH + g] = (_Float16)(acc[r] + bg2);
        }
    }
    __syncthreads();
    {
        f16x8* dst = (f16x8*)(xg2 + (size_t)b * SS * HH);
        const f16x8* src = (const f16x8*)gS;
        for (int i8 = t; i8 < SS * HH / 8; i8 += 512) dst[i8] = src[i8];
    }
}

// ---------------- Kernel 4: LSTM2 + fc, one batch per WAVE (R6 version) ----------------
__global__ __launch_bounds__(256) void k_lstm2(
    const _Float16* __restrict__ xg2,
    const float* __restrict__ l2_whh,
    const float* __restrict__ fc_w, const float* __restrict__ fc_b,
    float* __restrict__ out)
{
    __shared__ _Float16 hsb[4][SS * HSB];

    const int t = threadIdx.x, lane = t & 63, w = t >> 6;
    const int n = blockIdx.x * 4 + w;
    const int u16 = lane & 15;

    float whr[H2];
    #pragma unroll
    for (int j = 0; j < H2; j++) whr[j] = l2_whh[lane * H2 + j];

    const _Float16* xgp = xg2 + (size_t)n * SS * HH + lane;
    float h = 0.0f, c = 0.0f;
    _Float16 xv = xgp[0];

    for (int s = 0; s < SS; s++) {
        _Float16 xnext = (_Float16)0.0f;
        if (s + 1 < SS) xnext = xgp[(s + 1) * HH];   // prefetch (L2-hot)

        float a0 = (float)xv, a1 = 0.0f, a2 = 0.0f, a3 = 0.0f;
        #pragma unroll
        for (int j = 0; j < H2; j += 4) {
            a0 += rl(h, j)     * whr[j];
            a1 += rl(h, j + 1) * whr[j + 1];
            a2 += rl(h, j + 2) * whr[j + 2];
            a3 += rl(h, j + 3) * whr[j + 3];
        }
        float a = (a0 + a1) + (a2 + a3);
        float iv = __shfl(a, u16);
        float fv = __shfl(a, H2 + u16);
        float gv = __shfl(a, 2 * H2 + u16);
        float ov = __shfl(a, 3 * H2 + u16);
        c = sigm(fv) * c + sigm(iv) * tanh_f(gv);
        h = sigm(ov) * tanh_f(c);
        if (lane < H2) hsb[w][s * HSB + lane] = (_Float16)h;
        xv = xnext;
    }
    __syncthreads();

    // fc: lane handles rows s = lane, lane+64
    for (int s = lane; s < SS; s += 64) {
        float hr[H2];
        #pragma unroll
        for (int j = 0; j < H2; j++) hr[j] = (float)hsb[w][s * HSB + j];
        float* op = out + ((size_t)n * SS + s) * DD;
        #pragma unroll
        for (int d = 0; d < DD; d++) {
            float a = fc_b[d];
            #pragma unroll
            for (int j = 0; j < H2; j++) a += hr[j] * fc_w[d * H2 + j];
            op[d] = a;
        }
    }
}

extern "C" void kernel_launch(void* const* d_in, const int* in_sizes, int n_in,
                              void* d_out, int out_size, void* d_ws, size_t ws_size,
                              hipStream_t stream) {
    const float* x     = (const float*)d_in[0];
    const float* fv_w  = (const float*)d_in[1];
    const float* fv_b  = (const float*)d_in[2];
    const float* fk_w  = (const float*)d_in[3];
    const float* fk_b  = (const float*)d_in[4];
    const float* fq_w  = (const float*)d_in[5];
    const float* fq_b  = (const float*)d_in[6];
    const float* l1f_wih = (const float*)d_in[7];
    const float* l1f_whh = (const float*)d_in[8];
    const float* l1f_bih = (const float*)d_in[9];
    const float* l1f_bhh = (const float*)d_in[10];
    const float* l1b_wih = (const float*)d_in[11];
    const float* l1b_whh = (const float*)d_in[12];
    const float* l1b_bih = (const float*)d_in[13];
    const float* l1b_bhh = (const float*)d_in[14];
    const float* tv_w  = (const float*)d_in[15];
    const float* tv_b  = (const float*)d_in[16];
    const float* tk_w  = (const float*)d_in[17];
    const float* tk_b  = (const float*)d_in[18];
    const float* tq_w  = (const float*)d_in[19];
    const float* tq_b  = (const float*)d_in[20];
    const float* l2_wih = (const float*)d_in[21];
    const float* l2_whh = (const float*)d_in[22];
    const float* l2_bih = (const float*)d_in[23];
    const float* l2_bhh = (const float*)d_in[24];
    const float* fc_w  = (const float*)d_in[25];
    const float* fc_b  = (const float*)d_in[26];

    _Float16* fa16 = (_Float16*)d_ws;                      // B*FASTR f16 (3.18MB)
    _Float16* hf = fa16 + (size_t)BB * FASTR;              // B*S*H f16 (25.2MB)
    _Float16* hb = hf + (size_t)BB * SS * HH;              // B*S*H f16 (25.2MB)
    _Float16* w16 = hb + (size_t)BB * SS * HH;             // 16384 f16 (32KB)
    float* bsum = (float*)(w16 + 16384);                   // 64 f32
    _Float16* xg2 = hf;  // overlay: k_attn block b reads hf[b] first, writes xg2[b] last

    k_feat<<<BB, 128, 0, stream>>>(x, fv_w, fv_b, fk_w, fk_b, fq_w, fq_b,
        tv_w, tk_w, tq_w, l2_wih, l2_bih, l2_bhh, w16, bsum, fa16);
    k_bilstm<<<256, 256, 0, stream>>>(fa16,
        l1f_wih, l1f_whh, l1f_bih, l1f_bhh,
        l1b_wih, l1b_whh, l1b_bih, l1b_bhh, hf, hb);
    k_attn<<<BB, 512, 0, stream>>>(hf, hb,
        tv_b, tk_b, tq_b, w16, bsum, xg2);
    k_lstm2<<<512, 256, 0, stream>>>(xg2, l2_whh, fc_w, fc_b, (float*)d_out);
}